// Round 10
// baseline (260.777 us; speedup 1.0000x reference)
//
#include <hip/hip_runtime.h>

typedef __attribute__((ext_vector_type(8))) short short8;
typedef __attribute__((ext_vector_type(4))) float f32x4;

#define BB 16
#define MM 2048
#define NN 2048

static __device__ __forceinline__ unsigned int cvtpk(float lo, float hi) {
  unsigned int r;
  asm("v_cvt_pk_bf16_f32 %0, %1, %2" : "=v"(r) : "v"(lo), "v"(hi));
  return r;
}
static __device__ __forceinline__ float rdlane(float v, int l) {
  return __uint_as_float(__builtin_amdgcn_readlane(__float_as_uint(v), l));
}

#define WAITV(N)                                            \
  do {                                                      \
    asm volatile("s_waitcnt vmcnt(" #N ")" ::: "memory");   \
    __builtin_amdgcn_sched_barrier(0);                      \
  } while (0)
#define BAR() __builtin_amdgcn_s_barrier()

// in: [B, nrows, 64] f32 -> out: [B, 64, nrows] bf16
__global__ void transpose_cvt(const float* __restrict__ in,
                              unsigned short* __restrict__ out, int nrows) {
  __shared__ float t[64][65];
  int b = blockIdx.y;
  int n0 = blockIdx.x * 64;
  int tid = threadIdx.x;
  int lane = tid & 63;
  int q = tid >> 6;
  const float* inb = in + ((size_t)b * nrows + n0) * 64;
#pragma unroll
  for (int i = 0; i < 16; ++i) {
    int n = q * 16 + i;
    t[n][lane] = inb[n * 64 + lane];
  }
  __syncthreads();
  unsigned short* outb = out + (size_t)b * 64 * nrows + n0;
  int pr = tid & 31, rq = tid >> 5;
#pragma unroll
  for (int i = 0; i < 8; ++i) {
    int r = rq + 8 * i;
    int n = 2 * pr;
    *(unsigned int*)(outb + (size_t)r * nrows + n) = cvtpk(t[n][r], t[n + 1][r]);
  }
}

// Gram: bmat[b] = T * T^T, T = [64, K] bf16 row-major. No atomics:
// 4 waves split K, LDS reduce. grid (B), block 256.
__global__ void gemm_gram2(const unsigned short* __restrict__ tT,
                           float* __restrict__ bmat, int K) {
  __shared__ float part[4][64][65];
  int b = blockIdx.x;
  int tid = threadIdx.x;
  int w = tid >> 6, l = tid & 63;
  int lr = l & 15, g = l >> 4;
  const unsigned short* vb = tT + (size_t)b * 64 * K;
  int kslice = K >> 2;
  int kbase = w * kslice;
  f32x4 acc[4][4] = {};
  for (int kk = 0; kk < kslice; kk += 32) {
    int k = kbase + kk + 8 * g;
    short8 fr[4];
#pragma unroll
    for (int rt = 0; rt < 4; ++rt)
      fr[rt] = *(const short8*)(vb + (size_t)(rt * 16 + lr) * K + k);
#pragma unroll
    for (int rt = 0; rt < 4; ++rt)
#pragma unroll
      for (int ct = 0; ct < 4; ++ct)
        acc[rt][ct] = __builtin_amdgcn_mfma_f32_16x16x32_bf16(fr[rt], fr[ct], acc[rt][ct], 0, 0, 0);
  }
#pragma unroll
  for (int rt = 0; rt < 4; ++rt)
#pragma unroll
    for (int ct = 0; ct < 4; ++ct)
#pragma unroll
      for (int j = 0; j < 4; ++j)
        part[w][rt * 16 + 4 * g + j][ct * 16 + lr] = acc[rt][ct][j];
  __syncthreads();
  float* bb = bmat + b * 4096;
  for (int i = tid; i < 4096; i += 256) {
    int row = i >> 6, col = i & 63;
    bb[i] = part[0][row][col] + part[1][row][col] + part[2][row][col] + part[3][row][col];
  }
}

// a[b][m][r] = sum_n x[b][m][n] * v[b][n][r];  vT = [B,64,N] bf16
// DEEP-PIPELINED: 4 stage buffers, 3 chunks prefetched, counted
// s_waitcnt vmcnt(8) + raw s_barrier (never drain to 0 in the loop).
// [64 m][64 n] f32 tiles; source pre-swizzled (slot ^= row&7), read same XOR.
// grid (M/64, B), block 256.
__global__ void __launch_bounds__(256, 2)
gemm_xv(const float* __restrict__ x,
        const unsigned short* __restrict__ vT,
        float* __restrict__ a) {
  __shared__ char smem[65536];  // 4 x 16 KB stage buffers
  int b = blockIdx.y;
  int m0 = blockIdx.x * 64;
  int tid = threadIdx.x;
  int w = tid >> 6, l = tid & 63;
  int lr = l & 15, g = l >> 4;
  const unsigned short* vb = vT + (size_t)b * 64 * NN;
  const char* xg0 = (const char*)x + ((size_t)b * MM + m0) * (size_t)(NN * 4);
  f32x4 acc[4] = {};
  int rowb = (w * 16 + lr) * 256;  // this lane's A-row base in the tile
  int key = lr & 7;                // read-side swizzle key (= row&7)

  // 16 insts x 1 KB; inst s covers rows s*4+(l>>4), 256 B each; 4 per wave.
#define XVSTAGE(DB, CH)                                                         \
  {                                                                             \
    char* lbs = (char*)smem + (DB)*16384;                                       \
    _Pragma("unroll")                                                           \
    for (int i = 0; i < 4; ++i) {                                               \
      int s = w * 4 + i;                                                        \
      int lg = ((l & 15) ^ ((s & 1) * 4 + (l >> 4))) * 16;                      \
      const char* gp = xg0 + (size_t)(s * 4 + (l >> 4)) * (NN * 4) +            \
                       (CH)*256 + lg;                                           \
      __builtin_amdgcn_global_load_lds(                                         \
          (const __attribute__((address_space(1))) unsigned int*)gp,            \
          (__attribute__((address_space(3))) unsigned int*)(lbs + s * 1024),    \
          16, 0, 0);                                                            \
    }                                                                           \
  }

#define XVCOMP(C)                                                               \
  {                                                                             \
    const char* lb = (const char*)smem + ((C)&3) * 16384 + rowb;                \
    _Pragma("unroll")                                                           \
    for (int kh = 0; kh < 2; ++kh) {                                            \
      f32x4 lo = *(const f32x4*)(lb + ((kh * 8 + 2 * g + 0) ^ key) * 16);       \
      f32x4 hi = *(const f32x4*)(lb + ((kh * 8 + 2 * g + 1) ^ key) * 16);       \
      union { short8 s; unsigned int u[4]; } af;                                \
      af.u[0] = cvtpk(lo[0], lo[1]);                                            \
      af.u[1] = cvtpk(lo[2], lo[3]);                                            \
      af.u[2] = cvtpk(hi[0], hi[1]);                                            \
      af.u[3] = cvtpk(hi[2], hi[3]);                                            \
      int k = (C)*64 + kh * 32 + 8 * g;                                         \
      _Pragma("unroll")                                                         \
      for (int ct = 0; ct < 4; ++ct) {                                          \
        short8 bf = *(const short8*)(vb + (size_t)(ct * 16 + lr) * NN + k);     \
        acc[ct] = __builtin_amdgcn_mfma_f32_16x16x32_bf16(af.s, bf, acc[ct],    \
                                                          0, 0, 0);             \
      }                                                                         \
    }                                                                           \
  }

  XVSTAGE(0, 0); XVSTAGE(1, 1); XVSTAGE(2, 2);   // 12 loads/wave in flight
  for (int c = 0; c < 29; ++c) {
    WAITV(8); BAR();
    XVCOMP(c);
    XVSTAGE((c + 3) & 3, c + 3);
  }
  WAITV(8); BAR(); XVCOMP(29);
  WAITV(4); BAR(); XVCOMP(30);
  WAITV(0); BAR(); XVCOMP(31);
#undef XVSTAGE
#undef XVCOMP

  float* ab = a + ((size_t)b * MM + m0 + w * 16) * 64;
#pragma unroll
  for (int ct = 0; ct < 4; ++ct)
#pragma unroll
    for (int j = 0; j < 4; ++j)
      ab[(size_t)(4 * g + j) * 64 + ct * 16 + lr] = acc[ct][j];
}

// a[b][n][r] = sum_m x[b][m][n] * u[b][m][r];  uT = [B,64,M] bf16
// Same deep pipeline; [64 m][64 n] f32 x^T tiles; column reads with
// slot ^= ((m>>3)&1)<<2 both sides. Batch order reversed for L3 hits.
// grid (N/64, B), block 256.
__global__ void __launch_bounds__(256, 2)
gemm_xtu(const float* __restrict__ x,
         const unsigned short* __restrict__ uT,
         float* __restrict__ a) {
  __shared__ char smem[65536];  // 4 x 16 KB stage buffers
  int b = (BB - 1) - blockIdx.y;   // reverse-order second pass over x (L3)
  int n0 = blockIdx.x * 64;
  int tid = threadIdx.x;
  int w = tid >> 6, l = tid & 63;
  int lr = l & 15, g = l >> 4;
  const unsigned short* ub = uT + (size_t)b * 64 * MM;
  const char* xg0 = (const char*)x + ((size_t)b * MM * NN + n0) * 4;
  f32x4 acc[4] = {};
  int slotX = ((w * 4 + (lr >> 2)) ^ ((g & 1) << 2)) * 16 + (lr & 3) * 4;

#define XTSTAGE(DB, CH)                                                         \
  {                                                                             \
    char* lbs = (char*)smem + (DB)*16384;                                       \
    _Pragma("unroll")                                                           \
    for (int i = 0; i < 4; ++i) {                                               \
      int s = w * 4 + i;                                                        \
      int lg = ((l & 15) ^ (((s >> 1) & 1) << 2)) * 16;                         \
      const char* gp = xg0 + (size_t)((CH)*64 + s * 4 + (l >> 4)) * (NN * 4) +  \
                       lg;                                                      \
      __builtin_amdgcn_global_load_lds(                                         \
          (const __attribute__((address_space(1))) unsigned int*)gp,            \
          (__attribute__((address_space(3))) unsigned int*)(lbs + s * 1024),    \
          16, 0, 0);                                                            \
    }                                                                           \
  }

#define XTCOMP(C)                                                               \
  {                                                                             \
    const char* lb = (const char*)smem + ((C)&3) * 16384 + slotX;               \
    _Pragma("unroll")                                                           \
    for (int kh = 0; kh < 2; ++kh) {                                            \
      const char* lk = lb + (kh * 32 + 8 * g) * 256;                            \
      float vv[8];                                                              \
      _Pragma("unroll")                                                         \
      for (int j = 0; j < 8; ++j)                                               \
        vv[j] = *(const float*)(lk + j * 256);                                  \
      union { short8 s; unsigned int u[4]; } af;                                \
      af.u[0] = cvtpk(vv[0], vv[1]);                                            \
      af.u[1] = cvtpk(vv[2], vv[3]);                                            \
      af.u[2] = cvtpk(vv[4], vv[5]);                                            \
      af.u[3] = cvtpk(vv[6], vv[7]);                                            \
      int k = (C)*64 + kh * 32 + 8 * g;                                         \
      _Pragma("unroll")                                                         \
      for (int ct = 0; ct < 4; ++ct) {                                          \
        short8 bf = *(const short8*)(ub + (size_t)(ct * 16 + lr) * MM + k);     \
        acc[ct] = __builtin_amdgcn_mfma_f32_16x16x32_bf16(af.s, bf, acc[ct],    \
                                                          0, 0, 0);             \
      }                                                                         \
    }                                                                           \
  }

  XTSTAGE(0, 0); XTSTAGE(1, 1); XTSTAGE(2, 2);
  for (int c = 0; c < 29; ++c) {
    WAITV(8); BAR();
    XTCOMP(c);
    XTSTAGE((c + 3) & 3, c + 3);
  }
  WAITV(8); BAR(); XTCOMP(29);
  WAITV(4); BAR(); XTCOMP(30);
  WAITV(0); BAR(); XTCOMP(31);
#undef XTSTAGE
#undef XTCOMP

  float* ab = a + ((size_t)b * NN + n0 + w * 16) * 64;
#pragma unroll
  for (int ct = 0; ct < 4; ++ct)
#pragma unroll
    for (int j = 0; j < 4; ++j)
      ab[(size_t)(4 * g + j) * 64 + ct * 16 + lr] = acc[ct][j];
}

// Coordinate descent, one THREAD per row: u[64], a[64] live in VGPRs,
// b reads are thread-invariant -> s_load + SGPR fmac operands.
// grid (nrows/64, B), block 64 (1 wave).
__global__ void __launch_bounds__(64, 1)
cd_kernel2(const float* __restrict__ u_in,
           const float* __restrict__ a_ws,
           const float* __restrict__ bmat,
           float* __restrict__ u_out,
           float l1, float l2e, int nrows) {
  int b = blockIdx.y;
  int m = blockIdx.x * 64 + threadIdx.x;
  size_t base = ((size_t)b * nrows + m) * 64;
  const float* bb = bmat + b * 4096;
  float uu[64], aa[64];
#pragma unroll
  for (int i = 0; i < 16; ++i) {
    *(f32x4*)(uu + 4 * i) = *(const f32x4*)(u_in + base + 4 * i);
    *(f32x4*)(aa + 4 * i) = *(const f32x4*)(a_ws + base + 4 * i);
  }
  int lane = threadIdx.x;
  float invl = 1.0f / (bb[lane * 65] + l2e);
#pragma unroll
  for (int r = 0; r < 64; ++r) {
    float s0 = 0.f, s1 = 0.f, s2 = 0.f, s3 = 0.f;
#pragma unroll
    for (int j = 0; j < 64; j += 4) {
      s0 = fmaf(uu[j + 0], bb[r * 64 + j + 0], s0);
      s1 = fmaf(uu[j + 1], bb[r * 64 + j + 1], s1);
      s2 = fmaf(uu[j + 2], bb[r * 64 + j + 2], s2);
      s3 = fmaf(uu[j + 3], bb[r * 64 + j + 3], s3);
    }
    float s = (s0 + s1) + (s2 + s3);
    float brr = bb[r * 65];                      // uniform -> SGPR
    float num = fmaf(uu[r], brr, aa[r] - s);     // a_r - (s - u_r*b_rr)
    float cl = fminf(fmaxf(num, -l1), l1);       // v_med3
    uu[r] = (num - cl) * rdlane(invl, r);        // soft-thr / (b_rr+l2e)
  }
#pragma unroll
  for (int i = 0; i < 16; ++i)
    *(f32x4*)(u_out + base + 4 * i) = *(const f32x4*)(uu + 4 * i);
}

extern "C" void kernel_launch(void* const* d_in, const int* in_sizes, int n_in,
                              void* d_out, int out_size, void* d_ws, size_t ws_size,
                              hipStream_t stream) {
  (void)in_sizes; (void)n_in; (void)out_size; (void)ws_size;
  const float* x = (const float*)d_in[0];
  const float* u = (const float*)d_in[1];
  const float* v = (const float*)d_in[2];
  float* u_out = (float*)d_out;
  float* v_out = u_out + (size_t)BB * MM * 64;

  float* a_ws = (float*)d_ws;                                        // 8.39 MB
  float* b_ws = (float*)((char*)d_ws + (size_t)BB * MM * 64 * 4);    // 256 KB
  unsigned short* tT = (unsigned short*)((char*)b_ws + (size_t)BB * 4096 * 4);

  float l1u = (float)(0.01 * 0.1 * (double)NN);
  float l2u = (float)(0.01 * 0.9 * (double)NN + 1e-16);
  float l1v = (float)(0.01 * 0.1 * (double)MM);
  float l2v = (float)(0.01 * 0.9 * (double)MM + 1e-16);

  // ---- factor 0: update u ----
  transpose_cvt<<<dim3(NN / 64, BB), 256, 0, stream>>>(v, tT, NN);
  gemm_gram2<<<dim3(BB), 256, 0, stream>>>(tT, b_ws, NN);
  gemm_xv<<<dim3(MM / 64, BB), 256, 0, stream>>>(x, tT, a_ws);
  cd_kernel2<<<dim3(MM / 64, BB), 64, 0, stream>>>(u, a_ws, b_ws, u_out, l1u, l2u, MM);

  // ---- factor 1: update v (uses new u) ----
  transpose_cvt<<<dim3(MM / 64, BB), 256, 0, stream>>>(u_out, tT, MM);
  gemm_gram2<<<dim3(BB), 256, 0, stream>>>(tT, b_ws, MM);
  gemm_xtu<<<dim3(NN / 64, BB), 256, 0, stream>>>(x, tT, a_ws);
  cd_kernel2<<<dim3(NN / 64, BB), 64, 0, stream>>>(v, a_ws, b_ws, v_out, l1v, l2v, NN);
}